// Round 2
// baseline (106.062 us; speedup 1.0000x reference)
//
#include <hip/hip_runtime.h>
#include <hip/hip_bf16.h>
#include <cstdint>

// B=2048, C=256, P=15 (pad to 16), channels=512, groups=4 (128 ch each)
#define NTOT (2048 * 16)   // 32768 padded cols (n = b*16 + p)
#define NVALID_F 30720.0f
#define EPS_ 1e-5f

typedef __bf16 bf16x8 __attribute__((ext_vector_type(8)));
typedef float f32x16 __attribute__((ext_vector_type(16)));
typedef float f32x4 __attribute__((ext_vector_type(4)));
typedef unsigned short u16x8 __attribute__((ext_vector_type(8)));
typedef unsigned short u16x4 __attribute__((ext_vector_type(4)));

__device__ __forceinline__ unsigned short f2bf(float f) {
  unsigned u = __float_as_uint(f);
  u += 0x7FFFu + ((u >> 16) & 1u);   // RNE
  return (unsigned short)(u >> 16);
}
__device__ __forceinline__ float bf2f(unsigned short h) {
  return __uint_as_float((unsigned)h << 16);
}

// ---- prologue: conv_w f32 [4][128][128] -> bf16 MFMA fragments + zero Sums ----
// Wf[g][mt][ks][lane][j] = w[g][o=mt*32+(lane&31)][i=ks*16+(lane>>5)*8+j]
// (valid as B-operand frag of D=Y*W^T: lane -> col=o, k=i -- same lane map)
__global__ void k_wprep(const float* __restrict__ w, unsigned short* __restrict__ wf,
                        float* __restrict__ Sums) {
  int q = blockIdx.x * 256 + threadIdx.x;  // 0..8191
  Sums[q] = 0.f;                           // 512 ch * 16 floats (64B padded lines)
  int l = q & 63, ks = (q >> 6) & 7, mt = (q >> 9) & 3, g = q >> 11;
  int o = mt * 32 + (l & 31);
  int i = ks * 16 + (l >> 5) * 8;
  const float* src = w + ((size_t)(g * 128 + o) * 128 + i);
  u16x8 v;
#pragma unroll
  for (int j = 0; j < 8; ++j) v[j] = f2bf(src[j]);
  *(u16x8*)(wf + (size_t)q * 8) = v;
}

// ---- main: build Y (xs|tmp) for 2 batches, D[n][ch] = Y^T W^T via MFMA,
//      fused per-channel (sum, sumsq) partials -> atomics, packed bf16 Z store ----
__global__ __launch_bounds__(256, 3) void k_gemm(const float* __restrict__ x,
                                                 const unsigned short* __restrict__ wf,
                                                 unsigned short* __restrict__ Z,
                                                 float* __restrict__ Sums) {
  __shared__ unsigned short Yt[32 * 520];  // [col 0..31][ch 0..511], stride 520
  __shared__ float xs[3840];               // one b-slab f32
  const int t = threadIdx.x;
  const int b0 = blockIdx.x * 2;

  for (int bi = 0; bi < 2; ++bi) {
    const f32x4* xb4 = (const f32x4*)(x + (size_t)(b0 + bi) * 3840);
    f32x4* xs4 = (f32x4*)xs;
    for (int q = t; q < 960; q += 256) xs4[q] = xb4[q];
    __syncthreads();
    // thread t = input channel c
    float v[15];
#pragma unroll
    for (int p = 0; p < 15; ++p) v[p] = xs[t * 15 + p];
    float pm[5];
#pragma unroll
    for (int q = 0; q < 5; ++q) pm[q] = fmaxf(fmaxf(v[3 * q], v[3 * q + 1]), v[3 * q + 2]);
    float mq[5];
    mq[0] = fmaxf(fmaxf(pm[1], pm[2]), fmaxf(pm[3], pm[4]));
    mq[1] = fmaxf(fmaxf(pm[0], pm[2]), fmaxf(pm[3], pm[4]));
    mq[2] = fmaxf(fmaxf(pm[0], pm[1]), fmaxf(pm[3], pm[4]));
    mq[3] = fmaxf(fmaxf(pm[0], pm[1]), fmaxf(pm[2], pm[4]));
    mq[4] = fmaxf(fmaxf(pm[0], pm[1]), fmaxf(pm[2], pm[3]));
    const int c0 = bi * 16;
#pragma unroll
    for (int p = 0; p < 15; ++p) {
      Yt[(c0 + p) * 520 + t] = f2bf(v[p]);                     // xs -> ch 0..255
      Yt[(c0 + p) * 520 + 256 + t] = f2bf(mq[p / 3] - v[p]);   // tmp -> ch 256..511
    }
    Yt[(c0 + 15) * 520 + t] = 0;        // pad col -> exact 0 (sums unaffected)
    Yt[(c0 + 15) * 520 + 256 + t] = 0;
    __syncthreads();
  }

  // MFMA phase: wave g = group g. A-frag = Y (lane: row=n=l31, k=lh*8+j),
  // B-frag = W (lane: col=o=l31, k=lh*8+j). D[n][ch]: col(lane&31)=ch,
  // row=(r&3)+8*(r>>2)+4*lh = n_local.
  const int lane = t & 63, g = t >> 6;
  const int l31 = lane & 31, lh = lane >> 5;
  const bf16x8* Wfv = (const bf16x8*)wf;
  const int n0 = blockIdx.x * 32;

  bf16x8 bfr[8];
  const unsigned short* yrow = &Yt[l31 * 520 + g * 128 + lh * 8];
#pragma unroll
  for (int ks = 0; ks < 8; ++ks)
    bfr[ks] = *(const bf16x8*)(yrow + ks * 16);

  bf16x8 wrA[8], wrB[8];
#pragma unroll
  for (int ks = 0; ks < 8; ++ks)
    wrA[ks] = Wfv[(size_t)((g * 4 + 0) * 8 + ks) * 64 + lane];

#define MT_STEP(MT, CUR, NXT, PRE)                                              \
  do {                                                                          \
    if (PRE) {                                                                  \
      _Pragma("unroll") for (int ks = 0; ks < 8; ++ks)                          \
          NXT[ks] = Wfv[(size_t)((g * 4 + (MT) + 1) * 8 + ks) * 64 + lane];     \
    }                                                                           \
    f32x16 acc;                                                                 \
    _Pragma("unroll") for (int r = 0; r < 16; ++r) acc[r] = 0.f;                \
    _Pragma("unroll") for (int ks = 0; ks < 8; ++ks)                            \
        acc = __builtin_amdgcn_mfma_f32_32x32x16_bf16(bfr[ks], CUR[ks], acc, 0, 0, 0); \
    float s = 0.f, s2 = 0.f;                                                    \
    _Pragma("unroll") for (int r = 0; r < 16; ++r) {                            \
      float vv = acc[r]; s += vv; s2 = fmaf(vv, vv, s2);                        \
    }                                                                           \
    s += __shfl_xor(s, 32, 64);                                                 \
    s2 += __shfl_xor(s2, 32, 64);                                               \
    const int ch = g * 128 + (MT) * 32 + l31;                                   \
    if (lane < 32) {                                                            \
      unsafeAtomicAdd(&Sums[ch * 16], s);                                       \
      unsafeAtomicAdd(&Sums[ch * 16 + 1], s2);                                  \
    }                                                                           \
    unsigned short* zc = Z + (size_t)ch * NTOT + n0 + 4 * lh;                   \
    _Pragma("unroll") for (int q = 0; q < 4; ++q) {                             \
      u16x4 pk;                                                                 \
      _Pragma("unroll") for (int j = 0; j < 4; ++j) pk[j] = f2bf(acc[4 * q + j]); \
      *(u16x4*)(zc + 8 * q) = pk;                                               \
    }                                                                           \
  } while (0)

  MT_STEP(0, wrA, wrB, 1);
  MT_STEP(1, wrB, wrA, 1);
  MT_STEP(2, wrA, wrB, 1);
  MT_STEP(3, wrB, wrA, 0);
#undef MT_STEP
}

// ---- finalize: per-block AB from Sums, transpose [ch][n]->[b][ch][p],
//      fused affine + relu ----
__global__ __launch_bounds__(256, 3) void k_final(const unsigned short* __restrict__ Z,
                                                  const float* __restrict__ Sums,
                                                  const float* __restrict__ gamma,
                                                  const float* __restrict__ beta,
                                                  float* __restrict__ out) {
  __shared__ unsigned short zt[512 * 48];  // [ch][32 cols] stride 48 (96B, 16B-aligned)
  __shared__ float aArr[512], bArr[512];
  const int t = threadIdx.x;
  const int n0 = blockIdx.x * 32;

  // stage Z slab (issue loads first for latency)
#pragma unroll
  for (int it = 0; it < 8; ++it) {
    int q = it * 256 + t;          // 2048 chunks of 16B
    int ch = q >> 2, o = (q & 3) * 8;
    *(u16x8*)&zt[ch * 48 + o] = *(const u16x8*)(Z + (size_t)ch * NTOT + n0 + o);
  }
  // fold BN stats: out = relu(z*a + b)
  const float inv = 1.f / NVALID_F;
#pragma unroll
  for (int i = 0; i < 2; ++i) {
    int ch = i * 256 + t;
    float S = Sums[ch * 16], S2 = Sums[ch * 16 + 1];
    float mean = S * inv;
    float var = fmaxf(S2 * inv - mean * mean, 0.f);
    float a = gamma[ch] * rsqrtf(var + EPS_);
    aArr[ch] = a;
    bArr[ch] = beta[ch] - mean * a;
  }
  __syncthreads();

  const int b0 = blockIdx.x * 2;
#pragma unroll
  for (int bi = 0; bi < 2; ++bi) {
    float* slab = out + (size_t)(b0 + bi) * 7680;
#pragma unroll 6
    for (int k = 0; k < 30; ++k) {
      int e = k * 256 + t;
      int ch = e / 15, p = e - ch * 15;
      float val = bf2f(zt[ch * 48 + bi * 16 + p]);
      slab[e] = fmaxf(fmaf(val, aArr[ch], bArr[ch]), 0.f);
    }
  }
}

extern "C" void kernel_launch(void* const* d_in, const int* in_sizes, int n_in,
                              void* d_out, int out_size, void* d_ws, size_t ws_size,
                              hipStream_t stream) {
  const float* x = (const float*)d_in[0];
  const float* cw = (const float*)d_in[1];
  // d_in[2] = conv_b: cancelled exactly by training-mode BN -> unused
  const float* gamma = (const float*)d_in[3];
  const float* beta = (const float*)d_in[4];

  unsigned short* wf = (unsigned short*)d_ws;            // 65536 bf16 = 128 KB
  unsigned short* Z = wf + 65536;                        // 512*32768 bf16 = 32 MB
  float* Sums = (float*)(Z + (size_t)512 * NTOT);        // 512 ch * 16 f32 = 32 KB

  hipLaunchKernelGGL(k_wprep, dim3(32), dim3(256), 0, stream, cw, wf, Sums);
  hipLaunchKernelGGL(k_gemm, dim3(1024), dim3(256), 0, stream, x, wf, Z, Sums);
  hipLaunchKernelGGL(k_final, dim3(1024), dim3(256), 0, stream, Z, Sums, gamma, beta,
                     (float*)d_out);
}

// Round 4
// 49.845 us; speedup vs baseline: 2.1279x; 2.1279x over previous
//
#include <hip/hip_runtime.h>
#include <hip/hip_bf16.h>
#include <cstdint>

// B=2048, C=256, P=15, channels=512, groups=4 (128 ch each)
// Z2 layout: [n2][ch], n2 = b*15 + p  (no padding), 30720 x 512 bf16 = 30 MB
#define EPS_ 1e-5f
#define NVALID_F 30720.0f

typedef __bf16 bf16x8 __attribute__((ext_vector_type(8)));
typedef float f32x16 __attribute__((ext_vector_type(16)));
typedef unsigned short u16x8 __attribute__((ext_vector_type(8)));
typedef float f32x4a4 __attribute__((ext_vector_type(4), aligned(4)));
typedef float f32x2a4 __attribute__((ext_vector_type(2), aligned(4)));

__device__ __forceinline__ unsigned short f2bf(float f) {
  unsigned u = __float_as_uint(f);
  u += 0x7FFFu + ((u >> 16) & 1u);   // RNE
  return (unsigned short)(u >> 16);
}
__device__ __forceinline__ float bf2f(unsigned short h) {
  return __uint_as_float((unsigned)h << 16);
}

// ---- prologue: conv_w f32 [4][128][128] -> bf16 MFMA B-fragments ----
// Wf[g][mt][ks][lane][j] = w[g][o=mt*32+(lane&31)][i=ks*16+(lane>>5)*8+j]
__global__ void k_wprep(const float* __restrict__ w, unsigned short* __restrict__ wf) {
  int q = blockIdx.x * 256 + threadIdx.x;  // 0..8191
  int l = q & 63, ks = (q >> 6) & 7, mt = (q >> 9) & 3, g = q >> 11;
  int o = mt * 32 + (l & 31);
  int i = ks * 16 + (l >> 5) * 8;
  const float* src = w + ((size_t)(g * 128 + o) * 128 + i);
  u16x8 v;
#pragma unroll
  for (int j = 0; j < 8; ++j) v[j] = f2bf(src[j]);
  *(u16x8*)(wf + (size_t)q * 8) = v;
}

// ---- main: build Y (xs|tmp) for 2 batches, D[n][ch] = Y W^T via MFMA,
//      per-block (sum,sumsq) partials (NO atomics), packed [n][ch] Z store ----
__global__ __launch_bounds__(256, 3) void k_gemm(const float* __restrict__ x,
                                                 const unsigned short* __restrict__ wf,
                                                 unsigned short* __restrict__ Z2,
                                                 float2* __restrict__ Part) {
  __shared__ unsigned short Yt[32 * 520];  // [col 0..31][ch 0..511], stride 520
  const int t = threadIdx.x;
  const int b0 = blockIdx.x * 2;

#pragma unroll
  for (int bi = 0; bi < 2; ++bi) {
    // thread t = input channel; 15 contiguous floats straight from global
    const float* xb = x + (size_t)(b0 + bi) * 3840 + t * 15;
    f32x4a4 u0 = *(const f32x4a4*)(xb);
    f32x4a4 u1 = *(const f32x4a4*)(xb + 4);
    f32x4a4 u2 = *(const f32x4a4*)(xb + 8);
    f32x2a4 u3 = *(const f32x2a4*)(xb + 12);
    float u4 = xb[14];
    float v[15];
#pragma unroll
    for (int j = 0; j < 4; ++j) { v[j] = u0[j]; v[4 + j] = u1[j]; v[8 + j] = u2[j]; }
    v[12] = u3[0]; v[13] = u3[1]; v[14] = u4;
    float pm[5];
#pragma unroll
    for (int q = 0; q < 5; ++q) pm[q] = fmaxf(fmaxf(v[3 * q], v[3 * q + 1]), v[3 * q + 2]);
    float mq[5];
    mq[0] = fmaxf(fmaxf(pm[1], pm[2]), fmaxf(pm[3], pm[4]));
    mq[1] = fmaxf(fmaxf(pm[0], pm[2]), fmaxf(pm[3], pm[4]));
    mq[2] = fmaxf(fmaxf(pm[0], pm[1]), fmaxf(pm[3], pm[4]));
    mq[3] = fmaxf(fmaxf(pm[0], pm[1]), fmaxf(pm[2], pm[4]));
    mq[4] = fmaxf(fmaxf(pm[0], pm[1]), fmaxf(pm[2], pm[3]));
    const int c0 = bi * 16;
#pragma unroll
    for (int p = 0; p < 15; ++p) {
      Yt[(c0 + p) * 520 + t] = f2bf(v[p]);                     // xs -> ch 0..255
      Yt[(c0 + p) * 520 + 256 + t] = f2bf(mq[p / 3] - v[p]);   // tmp -> ch 256..511
    }
    Yt[(c0 + 15) * 520 + t] = 0;        // pad col feeds MFMA only (never stored)
    Yt[(c0 + 15) * 520 + 256 + t] = 0;
  }
  __syncthreads();

  // MFMA: wave g = group g. A-frag = Y rows (n), B-frag = W (ch).
  // D[col=ch via lane&31][row=n via (r&3)+8*(r>>2)+4*lh]  (validated r1/r2)
  const int lane = t & 63, g = t >> 6;
  const int l31 = lane & 31, lh = lane >> 5;
  const bf16x8* Wfv = (const bf16x8*)wf;

  bf16x8 bfr[8];
  const unsigned short* yrow = &Yt[l31 * 520 + g * 128 + lh * 8];
#pragma unroll
  for (int ks = 0; ks < 8; ++ks)
    bfr[ks] = *(const bf16x8*)(yrow + ks * 16);

  bf16x8 wrA[8], wrB[8];
#pragma unroll
  for (int ks = 0; ks < 8; ++ks)
    wrA[ks] = Wfv[(size_t)((g * 4 + 0) * 8 + ks) * 64 + lane];

#define MT_STEP(MT, CUR, NXT, PRE)                                              \
  do {                                                                          \
    if (PRE) {                                                                  \
      _Pragma("unroll") for (int ks = 0; ks < 8; ++ks)                          \
          NXT[ks] = Wfv[(size_t)((g * 4 + (MT) + 1) * 8 + ks) * 64 + lane];     \
    }                                                                           \
    f32x16 acc;                                                                 \
    _Pragma("unroll") for (int r = 0; r < 16; ++r) acc[r] = 0.f;                \
    _Pragma("unroll") for (int ks = 0; ks < 8; ++ks)                            \
        acc = __builtin_amdgcn_mfma_f32_32x32x16_bf16(bfr[ks], CUR[ks], acc, 0, 0, 0); \
    float s = 0.f, s2 = 0.f;                                                    \
    _Pragma("unroll") for (int r = 0; r < 16; ++r) {                            \
      float vv = acc[r]; s += vv; s2 = fmaf(vv, vv, s2);                        \
    }                                                                           \
    s += __shfl_xor(s, 32, 64);                                                 \
    s2 += __shfl_xor(s2, 32, 64);                                               \
    const int ch = g * 128 + (MT) * 32 + l31;                                   \
    if (lane < 32) Part[(size_t)blockIdx.x * 512 + ch] = make_float2(s, s2);    \
    _Pragma("unroll") for (int r = 0; r < 16; ++r) {                            \
      int row = (r & 3) + 8 * (r >> 2) + 4 * lh;                                \
      int p = row & 15, bl = row >> 4;                                          \
      if (p != 15)                                                              \
        Z2[((size_t)(b0 + bl) * 15 + p) * 512 + ch] = f2bf(acc[r]);             \
    }                                                                           \
  } while (0)

  MT_STEP(0, wrA, wrB, 1);
  MT_STEP(1, wrB, wrA, 1);
  MT_STEP(2, wrA, wrB, 1);
  MT_STEP(3, wrB, wrA, 0);
#undef MT_STEP
}

// ---- reduce per-block partials -> folded (a,b) per channel ----
__global__ void k_stats(const float2* __restrict__ Part,
                        const float* __restrict__ gamma, const float* __restrict__ beta,
                        float2* __restrict__ AB) {
  const int ch = blockIdx.x, t = threadIdx.x;
  float s = 0.f, s2 = 0.f;
#pragma unroll
  for (int i = 0; i < 4; ++i) {
    float2 v = Part[(size_t)(t + 256 * i) * 512 + ch];
    s += v.x; s2 += v.y;
  }
#pragma unroll
  for (int m = 32; m >= 1; m >>= 1) { s += __shfl_xor(s, m, 64); s2 += __shfl_xor(s2, m, 64); }
  __shared__ float ls[4], ls2[4];
  if ((t & 63) == 0) { ls[t >> 6] = s; ls2[t >> 6] = s2; }
  __syncthreads();
  if (t == 0) {
    float S = ls[0] + ls[1] + ls[2] + ls[3];
    float S2 = ls2[0] + ls2[1] + ls2[2] + ls2[3];
    const float inv = 1.f / NVALID_F;
    float mean = S * inv;
    float var = fmaxf(S2 * inv - mean * mean, 0.f);
    float a = gamma[ch] * rsqrtf(var + EPS_);
    AB[ch] = make_float2(a, beta[ch] - mean * a);
  }
}

// ---- finalize: contiguous Z2 slab -> LDS, transpose to [b][ch][p],
//      fused affine + relu, float2 stores ----
// Slab for 2 batches = 2*15*512 = 15360 shorts = 1920 u16x8 chunks.
__global__ __launch_bounds__(256, 3) void k_final(const unsigned short* __restrict__ Z2,
                                                  const float2* __restrict__ AB,
                                                  float* __restrict__ out) {
  __shared__ unsigned short zt[30 * 520];  // [row 0..29][ch 0..511], stride 520
  __shared__ float aArr[512], bArr[512];
  const int t = threadIdx.x;
  const int b0 = blockIdx.x * 2;

  const u16x8* src = (const u16x8*)(Z2 + (size_t)b0 * 15 * 512);
#pragma unroll
  for (int c = t; c < 1920; c += 256) {   // FIX r3: 1920 chunks (was 3840 -> LDS overflow)
    int row = c >> 6, off = (c & 63) * 8;
    *(u16x8*)&zt[row * 520 + off] = src[c];
  }
#pragma unroll
  for (int i = 0; i < 2; ++i) {
    int ch = i * 256 + t;
    float2 ab = AB[ch];
    aArr[ch] = ab.x; bArr[ch] = ab.y;
  }
  __syncthreads();

#pragma unroll
  for (int bi = 0; bi < 2; ++bi) {
    float2* slab = (float2*)(out + (size_t)(b0 + bi) * 7680);
#pragma unroll 5
    for (int k = 0; k < 15; ++k) {
      int e0 = k * 512 + 2 * t;
      int ch0 = e0 / 15, p0 = e0 - ch0 * 15;
      int e1 = e0 + 1;
      int ch1 = e1 / 15, p1 = e1 - ch1 * 15;
      float f0 = bf2f(zt[(bi * 15 + p0) * 520 + ch0]);
      float f1 = bf2f(zt[(bi * 15 + p1) * 520 + ch1]);
      slab[k * 256 + t] = make_float2(
          fmaxf(fmaf(f0, aArr[ch0], bArr[ch0]), 0.f),
          fmaxf(fmaf(f1, aArr[ch1], bArr[ch1]), 0.f));
    }
  }
}

extern "C" void kernel_launch(void* const* d_in, const int* in_sizes, int n_in,
                              void* d_out, int out_size, void* d_ws, size_t ws_size,
                              hipStream_t stream) {
  const float* x = (const float*)d_in[0];
  const float* cw = (const float*)d_in[1];
  // d_in[2] = conv_b: cancelled exactly by training-mode BN -> unused
  const float* gamma = (const float*)d_in[3];
  const float* beta = (const float*)d_in[4];

  unsigned short* wf = (unsigned short*)d_ws;             // 8192*8 bf16 = 128 KB
  unsigned short* Z2 = wf + 65536;                        // 30720*512 bf16 = 30 MB
  float2* Part = (float2*)(Z2 + (size_t)30720 * 512);     // 1024*512 float2 = 4 MB
  float2* AB = Part + (size_t)1024 * 512;                 // 512 float2 = 4 KB

  hipLaunchKernelGGL(k_wprep, dim3(32), dim3(256), 0, stream, cw, wf);
  hipLaunchKernelGGL(k_gemm, dim3(1024), dim3(256), 0, stream, x, wf, Z2, Part);
  hipLaunchKernelGGL(k_stats, dim3(512), dim3(256), 0, stream, Part, gamma, beta, AB);
  hipLaunchKernelGGL(k_final, dim3(1024), dim3(256), 0, stream, Z2, AB, (float*)d_out);
}

// Round 6
// 48.543 us; speedup vs baseline: 2.1849x; 1.0268x over previous
//
#include <hip/hip_runtime.h>
#include <hip/hip_bf16.h>
#include <cstdint>

// B=2048, C=256, P=15, channels=512, groups=4 (128 ch each)
// Recompute structure: pass1 computes BN stats (GEMM, discard z);
// pass2 recomputes z (x is L3-hot) and finalizes. z never hits HBM.
#define EPS_ 1e-5f
#define NVALID_F 30720.0f

typedef __bf16 bf16x8 __attribute__((ext_vector_type(8)));
typedef float f32x16 __attribute__((ext_vector_type(16)));
typedef unsigned short u16x8 __attribute__((ext_vector_type(8)));
typedef float f32x4a4 __attribute__((ext_vector_type(4), aligned(4)));
typedef float f32x2a4 __attribute__((ext_vector_type(2), aligned(4)));

__device__ __forceinline__ unsigned short f2bf(float f) {
  unsigned u = __float_as_uint(f);
  u += 0x7FFFu + ((u >> 16) & 1u);   // RNE
  return (unsigned short)(u >> 16);
}
__device__ __forceinline__ float bf2f(unsigned short h) {
  return __uint_as_float((unsigned)h << 16);
}

// ---- prologue: conv_w f32 [4][128][128] -> bf16 MFMA B-fragments ----
// Wf[g][mt][ks][lane][j] = w[g][o=mt*32+(lane&31)][i=ks*16+(lane>>5)*8+j]
__global__ void k_wprep(const float* __restrict__ w, unsigned short* __restrict__ wf) {
  int q = blockIdx.x * 256 + threadIdx.x;  // 0..8191
  int l = q & 63, ks = (q >> 6) & 7, mt = (q >> 9) & 3, g = q >> 11;
  int o = mt * 32 + (l & 31);
  int i = ks * 16 + (l >> 5) * 8;
  const float* src = w + ((size_t)(g * 128 + o) * 128 + i);
  u16x8 v;
#pragma unroll
  for (int j = 0; j < 8; ++j) v[j] = f2bf(src[j]);
  *(u16x8*)(wf + (size_t)q * 8) = v;
}

// Shared phase-A: build Y (xs | tmp) for 2 batches into Yt[32*520]
__device__ __forceinline__ void build_Y(const float* __restrict__ x, int b0, int t,
                                        unsigned short* __restrict__ Yt) {
#pragma unroll
  for (int bi = 0; bi < 2; ++bi) {
    const float* xb = x + (size_t)(b0 + bi) * 3840 + t * 15;
    f32x4a4 u0 = *(const f32x4a4*)(xb);
    f32x4a4 u1 = *(const f32x4a4*)(xb + 4);
    f32x4a4 u2 = *(const f32x4a4*)(xb + 8);
    f32x2a4 u3 = *(const f32x2a4*)(xb + 12);
    float u4 = xb[14];
    float v[15];
#pragma unroll
    for (int j = 0; j < 4; ++j) { v[j] = u0[j]; v[4 + j] = u1[j]; v[8 + j] = u2[j]; }
    v[12] = u3[0]; v[13] = u3[1]; v[14] = u4;
    float pm[5];
#pragma unroll
    for (int q = 0; q < 5; ++q) pm[q] = fmaxf(fmaxf(v[3 * q], v[3 * q + 1]), v[3 * q + 2]);
    float mq[5];
    mq[0] = fmaxf(fmaxf(pm[1], pm[2]), fmaxf(pm[3], pm[4]));
    mq[1] = fmaxf(fmaxf(pm[0], pm[2]), fmaxf(pm[3], pm[4]));
    mq[2] = fmaxf(fmaxf(pm[0], pm[1]), fmaxf(pm[3], pm[4]));
    mq[3] = fmaxf(fmaxf(pm[0], pm[1]), fmaxf(pm[2], pm[4]));
    mq[4] = fmaxf(fmaxf(pm[0], pm[1]), fmaxf(pm[2], pm[3]));
    const int c0 = bi * 16;
#pragma unroll
    for (int p = 0; p < 15; ++p) {
      Yt[(c0 + p) * 520 + t] = f2bf(v[p]);                     // xs -> ch 0..255
      Yt[(c0 + p) * 520 + 256 + t] = f2bf(mq[p / 3] - v[p]);   // tmp -> ch 256..511
    }
    Yt[(c0 + 15) * 520 + t] = 0;        // pad row: exact 0 (stats unaffected)
    Yt[(c0 + 15) * 520 + 256 + t] = 0;
  }
}

// ---- pass 1: GEMM, per-block (sum,sumsq) partials only; z discarded ----
__global__ __launch_bounds__(256, 3) void k_pass1(const float* __restrict__ x,
                                                  const unsigned short* __restrict__ wf,
                                                  float2* __restrict__ Part) {
  __shared__ unsigned short Yt[32 * 520];
  const int t = threadIdx.x;
  const int b0 = blockIdx.x * 2;
  build_Y(x, b0, t, Yt);
  __syncthreads();

  const int lane = t & 63, g = t >> 6;
  const int l31 = lane & 31, lh = lane >> 5;
  const bf16x8* Wfv = (const bf16x8*)wf;

  bf16x8 bfr[8];
  const unsigned short* yrow = &Yt[l31 * 520 + g * 128 + lh * 8];
#pragma unroll
  for (int ks = 0; ks < 8; ++ks)
    bfr[ks] = *(const bf16x8*)(yrow + ks * 16);

  bf16x8 wrA[8], wrB[8];
#pragma unroll
  for (int ks = 0; ks < 8; ++ks)
    wrA[ks] = Wfv[(size_t)((g * 4 + 0) * 8 + ks) * 64 + lane];

#define MT_STEP1(MT, CUR, NXT, PRE)                                             \
  do {                                                                          \
    if (PRE) {                                                                  \
      _Pragma("unroll") for (int ks = 0; ks < 8; ++ks)                          \
          NXT[ks] = Wfv[(size_t)((g * 4 + (MT) + 1) * 8 + ks) * 64 + lane];     \
    }                                                                           \
    f32x16 acc;                                                                 \
    _Pragma("unroll") for (int r = 0; r < 16; ++r) acc[r] = 0.f;                \
    _Pragma("unroll") for (int ks = 0; ks < 8; ++ks)                            \
        acc = __builtin_amdgcn_mfma_f32_32x32x16_bf16(bfr[ks], CUR[ks], acc, 0, 0, 0); \
    float s = 0.f, s2 = 0.f;                                                    \
    _Pragma("unroll") for (int r = 0; r < 16; ++r) {                            \
      float vv = acc[r]; s += vv; s2 = fmaf(vv, vv, s2);                        \
    }                                                                           \
    s += __shfl_xor(s, 32, 64);                                                 \
    s2 += __shfl_xor(s2, 32, 64);                                               \
    const int ch = g * 128 + (MT) * 32 + l31;                                   \
    if (lane < 32) Part[(size_t)blockIdx.x * 512 + ch] = make_float2(s, s2);    \
  } while (0)

  MT_STEP1(0, wrA, wrB, 1);
  MT_STEP1(1, wrB, wrA, 1);
  MT_STEP1(2, wrA, wrB, 1);
  MT_STEP1(3, wrB, wrA, 0);
#undef MT_STEP1
}

// ---- reduce per-block partials -> folded (a,b) per channel ----
__global__ void k_stats(const float2* __restrict__ Part,
                        const float* __restrict__ gamma, const float* __restrict__ beta,
                        float2* __restrict__ AB) {
  const int ch = blockIdx.x, t = threadIdx.x;
  float s = 0.f, s2 = 0.f;
#pragma unroll
  for (int i = 0; i < 4; ++i) {
    float2 v = Part[(size_t)(t + 256 * i) * 512 + ch];
    s += v.x; s2 += v.y;
  }
#pragma unroll
  for (int m = 32; m >= 1; m >>= 1) { s += __shfl_xor(s, m, 64); s2 += __shfl_xor(s2, m, 64); }
  __shared__ float ls[4], ls2[4];
  if ((t & 63) == 0) { ls[t >> 6] = s; ls2[t >> 6] = s2; }
  __syncthreads();
  if (t == 0) {
    float S = ls[0] + ls[1] + ls[2] + ls[3];
    float S2 = ls2[0] + ls2[1] + ls2[2] + ls2[3];
    const float inv = 1.f / NVALID_F;
    float mean = S * inv;
    float var = fmaxf(S2 * inv - mean * mean, 0.f);
    float a = gamma[ch] * rsqrtf(var + EPS_);
    AB[ch] = make_float2(a, beta[ch] - mean * a);
  }
}

// ---- pass 2: recompute GEMM (x is L3-hot), z-tile -> LDS, finalize ----
__global__ __launch_bounds__(256, 3) void k_pass2(const float* __restrict__ x,
                                                  const unsigned short* __restrict__ wf,
                                                  const float2* __restrict__ AB,
                                                  float* __restrict__ out) {
  __shared__ unsigned short Yt[32 * 520];
  __shared__ float aArr[512], bArr[512];
  const int t = threadIdx.x;
  const int b0 = blockIdx.x * 2;
  build_Y(x, b0, t, Yt);
  __syncthreads();

  {
    const int lane = t & 63, g = t >> 6;
    const int l31 = lane & 31, lh = lane >> 5;
    const bf16x8* Wfv = (const bf16x8*)wf;

    bf16x8 bfr[8];
    const unsigned short* yrow = &Yt[l31 * 520 + g * 128 + lh * 8];
#pragma unroll
    for (int ks = 0; ks < 8; ++ks)
      bfr[ks] = *(const bf16x8*)(yrow + ks * 16);
    // stage AB -> LDS (doesn't touch Yt; visible after the barrier below)
#pragma unroll
    for (int i = 0; i < 2; ++i) {
      int ch = i * 256 + t;
      float2 ab = AB[ch];
      aArr[ch] = ab.x; bArr[ch] = ab.y;
    }

    bf16x8 wrA[8], wrB[8];
#pragma unroll
    for (int ks = 0; ks < 8; ++ks)
      wrA[ks] = Wfv[(size_t)((g * 4 + 0) * 8 + ks) * 64 + lane];

    // Each wave reads (bfr, above) and writes back ONLY its own group's
    // 128-ch column range -> no inter-wave hazard before the final barrier.
#define MT_STEP2(MT, CUR, NXT, PRE)                                             \
  do {                                                                          \
    if (PRE) {                                                                  \
      _Pragma("unroll") for (int ks = 0; ks < 8; ++ks)                          \
          NXT[ks] = Wfv[(size_t)((g * 4 + (MT) + 1) * 8 + ks) * 64 + lane];     \
    }                                                                           \
    f32x16 acc;                                                                 \
    _Pragma("unroll") for (int r = 0; r < 16; ++r) acc[r] = 0.f;                \
    _Pragma("unroll") for (int ks = 0; ks < 8; ++ks)                            \
        acc = __builtin_amdgcn_mfma_f32_32x32x16_bf16(bfr[ks], CUR[ks], acc, 0, 0, 0); \
    const int ch = g * 128 + (MT) * 32 + l31;                                   \
    _Pragma("unroll") for (int r = 0; r < 16; ++r) {                            \
      int row = (r & 3) + 8 * (r >> 2) + 4 * lh;                                \
      Yt[row * 520 + ch] = f2bf(acc[r]);   /* pad rows written, never read */   \
    }                                                                           \
  } while (0)

    MT_STEP2(0, wrA, wrB, 1);
    MT_STEP2(1, wrB, wrA, 1);
    MT_STEP2(2, wrA, wrB, 1);
    MT_STEP2(3, wrB, wrA, 0);
#undef MT_STEP2
  }
  __syncthreads();   // z-tile + aArr/bArr visible to all waves

#pragma unroll
  for (int bi = 0; bi < 2; ++bi) {
    float2* slab = (float2*)(out + (size_t)(b0 + bi) * 7680);
#pragma unroll 5
    for (int k = 0; k < 15; ++k) {
      int e0 = k * 512 + 2 * t;
      int ch0 = e0 / 15, p0 = e0 - ch0 * 15;
      int e1 = e0 + 1;
      int ch1 = e1 / 15, p1 = e1 - ch1 * 15;
      float f0 = bf2f(Yt[(bi * 16 + p0) * 520 + ch0]);   // row = bi*16+p
      float f1 = bf2f(Yt[(bi * 16 + p1) * 520 + ch1]);
      slab[k * 256 + t] = make_float2(
          fmaxf(fmaf(f0, aArr[ch0], bArr[ch0]), 0.f),
          fmaxf(fmaf(f1, aArr[ch1], bArr[ch1]), 0.f));
    }
  }
}

extern "C" void kernel_launch(void* const* d_in, const int* in_sizes, int n_in,
                              void* d_out, int out_size, void* d_ws, size_t ws_size,
                              hipStream_t stream) {
  const float* x = (const float*)d_in[0];
  const float* cw = (const float*)d_in[1];
  // d_in[2] = conv_b: cancelled exactly by training-mode BN -> unused
  const float* gamma = (const float*)d_in[3];
  const float* beta = (const float*)d_in[4];

  unsigned short* wf = (unsigned short*)d_ws;             // 8192*8 bf16 = 128 KB
  float2* Part = (float2*)(wf + 65536);                   // 1024*512 float2 = 4 MB
  float2* AB = Part + (size_t)1024 * 512;                 // 512 float2 = 4 KB

  hipLaunchKernelGGL(k_wprep, dim3(32), dim3(256), 0, stream, cw, wf);
  hipLaunchKernelGGL(k_pass1, dim3(1024), dim3(256), 0, stream, x, wf, Part);
  hipLaunchKernelGGL(k_stats, dim3(512), dim3(256), 0, stream, Part, gamma, beta, AB);
  hipLaunchKernelGGL(k_pass2, dim3(1024), dim3(256), 0, stream, x, wf, AB, (float*)d_out);
}

// Round 7
// 48.269 us; speedup vs baseline: 2.1973x; 1.0057x over previous
//
#include <hip/hip_runtime.h>
#include <hip/hip_bf16.h>
#include <cstdint>

// B=2048, C=256, P=15, channels=512, groups=4 (128 ch each)
// Recompute structure (r6) + occupancy/coalescing fixes:
//  pass1: stats only (z discarded); pass2: recompute z in LDS, finalize.
//  x is staged THROUGH the Yt buffer (union) -> 4 blocks/CU both passes.
#define EPS_ 1e-5f
#define NVALID_F 30720.0f

typedef __bf16 bf16x8 __attribute__((ext_vector_type(8)));
typedef float f32x16 __attribute__((ext_vector_type(16)));
typedef float f32x4 __attribute__((ext_vector_type(4)));
typedef unsigned short u16x8 __attribute__((ext_vector_type(8)));

__device__ __forceinline__ unsigned short f2bf(float f) {
  unsigned u = __float_as_uint(f);
  u += 0x7FFFu + ((u >> 16) & 1u);   // RNE
  return (unsigned short)(u >> 16);
}
__device__ __forceinline__ float bf2f(unsigned short h) {
  return __uint_as_float((unsigned)h << 16);
}

// ---- prologue: conv_w f32 [4][128][128] -> bf16 MFMA B-fragments ----
// Wf[g][mt][ks][lane][j] = w[g][o=mt*32+(lane&31)][i=ks*16+(lane>>5)*8+j]
__global__ void k_wprep(const float* __restrict__ w, unsigned short* __restrict__ wf) {
  int q = blockIdx.x * 256 + threadIdx.x;  // 0..8191
  int l = q & 63, ks = (q >> 6) & 7, mt = (q >> 9) & 3, g = q >> 11;
  int o = mt * 32 + (l & 31);
  int i = ks * 16 + (l >> 5) * 8;
  const float* src = w + ((size_t)(g * 128 + o) * 128 + i);
  u16x8 v;
#pragma unroll
  for (int j = 0; j < 8; ++j) v[j] = f2bf(src[j]);
  *(u16x8*)(wf + (size_t)q * 8) = v;
}

// Build phase shared by both passes:
// stage 2 x-slabs (30720B f32, coalesced) INTO Yt's storage, read 30 f32/thread
// to registers, then overwrite Yt with bf16 Y = [xs | tmp].
__device__ __forceinline__ void build_Y_union(const float* __restrict__ x, int b0, int t,
                                              unsigned short* __restrict__ Yt) {
  {
    const f32x4* src = (const f32x4*)(x + (size_t)b0 * 3840);
    f32x4* dst = (f32x4*)Yt;
    for (int q = t; q < 1920; q += 256) dst[q] = src[q];   // 2 slabs, fully coalesced
  }
  __syncthreads();
  float v[2][15];
  const float* xsf = (const float*)Yt;
#pragma unroll
  for (int bi = 0; bi < 2; ++bi)
#pragma unroll
    for (int p = 0; p < 15; ++p) v[bi][p] = xsf[bi * 3840 + t * 15 + p];
  __syncthreads();   // all reads done before Yt overwrite
#pragma unroll
  for (int bi = 0; bi < 2; ++bi) {
    float pm[5];
#pragma unroll
    for (int q = 0; q < 5; ++q)
      pm[q] = fmaxf(fmaxf(v[bi][3 * q], v[bi][3 * q + 1]), v[bi][3 * q + 2]);
    float mq[5];
    mq[0] = fmaxf(fmaxf(pm[1], pm[2]), fmaxf(pm[3], pm[4]));
    mq[1] = fmaxf(fmaxf(pm[0], pm[2]), fmaxf(pm[3], pm[4]));
    mq[2] = fmaxf(fmaxf(pm[0], pm[1]), fmaxf(pm[3], pm[4]));
    mq[3] = fmaxf(fmaxf(pm[0], pm[1]), fmaxf(pm[2], pm[4]));
    mq[4] = fmaxf(fmaxf(pm[0], pm[1]), fmaxf(pm[2], pm[3]));
    const int c0 = bi * 16;
#pragma unroll
    for (int p = 0; p < 15; ++p) {
      Yt[(c0 + p) * 520 + t] = f2bf(v[bi][p]);                      // xs -> ch 0..255
      Yt[(c0 + p) * 520 + 256 + t] = f2bf(mq[p / 3] - v[bi][p]);    // tmp -> ch 256..511
    }
    Yt[(c0 + 15) * 520 + t] = 0;        // pad row: exact 0
    Yt[(c0 + 15) * 520 + 256 + t] = 0;
  }
}

// ---- pass 1: GEMM, per-block (sum,sumsq) partials only ----
__global__ __launch_bounds__(256, 4) void k_pass1(const float* __restrict__ x,
                                                  const unsigned short* __restrict__ wf,
                                                  float2* __restrict__ Part) {
  __shared__ __align__(16) unsigned short Yt[32 * 520];   // 33280 B -> 4 blocks/CU
  const int t = threadIdx.x;
  const int b0 = blockIdx.x * 2;
  build_Y_union(x, b0, t, Yt);
  __syncthreads();

  const int lane = t & 63, g = t >> 6;
  const int l31 = lane & 31, lh = lane >> 5;
  const bf16x8* Wfv = (const bf16x8*)wf;

  bf16x8 bfr[8];
  const unsigned short* yrow = &Yt[l31 * 520 + g * 128 + lh * 8];
#pragma unroll
  for (int ks = 0; ks < 8; ++ks)
    bfr[ks] = *(const bf16x8*)(yrow + ks * 16);

  for (int mt = 0; mt < 4; ++mt) {
    bf16x8 wr[8];
#pragma unroll
    for (int ks = 0; ks < 8; ++ks)
      wr[ks] = Wfv[(size_t)((g * 4 + mt) * 8 + ks) * 64 + lane];
    f32x16 acc;
#pragma unroll
    for (int r = 0; r < 16; ++r) acc[r] = 0.f;
#pragma unroll
    for (int ks = 0; ks < 8; ++ks)
      acc = __builtin_amdgcn_mfma_f32_32x32x16_bf16(bfr[ks], wr[ks], acc, 0, 0, 0);
    float s = 0.f, s2 = 0.f;
#pragma unroll
    for (int r = 0; r < 16; ++r) { float vv = acc[r]; s += vv; s2 = fmaf(vv, vv, s2); }
    s += __shfl_xor(s, 32, 64);
    s2 += __shfl_xor(s2, 32, 64);
    const int ch = g * 128 + mt * 32 + l31;
    if (lane < 32) Part[(size_t)blockIdx.x * 512 + ch] = make_float2(s, s2);
  }
}

// ---- stats: 64 blocks x 8 ch; dense 64B-line reads of Part ----
__global__ void k_stats(const float2* __restrict__ Part,
                        const float* __restrict__ gamma, const float* __restrict__ beta,
                        float2* __restrict__ AB) {
  const int t = threadIdx.x;
  const int chb = blockIdx.x * 8;
  const int c = t & 7, r0 = t >> 3;     // 32 rows x 8 ch
  float s = 0.f, s2 = 0.f;
  for (int k = 0; k < 32; ++k) {
    float2 vv = Part[(size_t)(r0 + 32 * k) * 512 + chb + c];
    s += vv.x; s2 += vv.y;
  }
  // reduce over r0 bits within wave (lane bits 3,4,5)
  s += __shfl_xor(s, 8, 64);  s2 += __shfl_xor(s2, 8, 64);
  s += __shfl_xor(s, 16, 64); s2 += __shfl_xor(s2, 16, 64);
  s += __shfl_xor(s, 32, 64); s2 += __shfl_xor(s2, 32, 64);
  __shared__ float2 red[4][8];
  if ((t & 63) < 8) red[t >> 6][c] = make_float2(s, s2);
  __syncthreads();
  if (t < 8) {
    float S = 0.f, S2 = 0.f;
#pragma unroll
    for (int w = 0; w < 4; ++w) { S += red[w][t].x; S2 += red[w][t].y; }
    const float inv = 1.f / NVALID_F;
    float mean = S * inv;
    float var = fmaxf(S2 * inv - mean * mean, 0.f);
    float a = gamma[chb + t] * rsqrtf(var + EPS_);
    AB[chb + t] = make_float2(a, beta[chb + t] - mean * a);
  }
}

// ---- pass 2: recompute GEMM (x L3-hot), z-tile in LDS, finalize ----
__global__ __launch_bounds__(256, 4) void k_pass2(const float* __restrict__ x,
                                                  const unsigned short* __restrict__ wf,
                                                  const float2* __restrict__ AB,
                                                  float* __restrict__ out) {
  __shared__ __align__(16) unsigned short Yt[32 * 520];
  __shared__ float aArr[512], bArr[512];   // 37376 B total -> 4 blocks/CU
  const int t = threadIdx.x;
  const int b0 = blockIdx.x * 2;

  // stage AB early (separate LDS region; visible after later barriers)
#pragma unroll
  for (int i = 0; i < 2; ++i) {
    int ch = i * 256 + t;
    float2 ab = AB[ch];
    aArr[ch] = ab.x; bArr[ch] = ab.y;
  }
  build_Y_union(x, b0, t, Yt);
  __syncthreads();

  {
    const int lane = t & 63, g = t >> 6;
    const int l31 = lane & 31, lh = lane >> 5;
    const bf16x8* Wfv = (const bf16x8*)wf;

    bf16x8 bfr[8];
    const unsigned short* yrow = &Yt[l31 * 520 + g * 128 + lh * 8];
#pragma unroll
    for (int ks = 0; ks < 8; ++ks)
      bfr[ks] = *(const bf16x8*)(yrow + ks * 16);

    // wave g reads+writes only cols [g*128, g*128+128) -> no inter-wave hazard
    for (int mt = 0; mt < 4; ++mt) {
      bf16x8 wr[8];
#pragma unroll
      for (int ks = 0; ks < 8; ++ks)
        wr[ks] = Wfv[(size_t)((g * 4 + mt) * 8 + ks) * 64 + lane];
      f32x16 acc;
#pragma unroll
      for (int r = 0; r < 16; ++r) acc[r] = 0.f;
#pragma unroll
      for (int ks = 0; ks < 8; ++ks)
        acc = __builtin_amdgcn_mfma_f32_32x32x16_bf16(bfr[ks], wr[ks], acc, 0, 0, 0);
      const int ch = g * 128 + mt * 32 + l31;
#pragma unroll
      for (int r = 0; r < 16; ++r) {
        int row = (r & 3) + 8 * (r >> 2) + 4 * lh;
        Yt[row * 520 + ch] = f2bf(acc[r]);   // pad rows written, never read
      }
    }
  }
  __syncthreads();   // z-tile visible to all waves

#pragma unroll
  for (int bi = 0; bi < 2; ++bi) {
    float2* slab = (float2*)(out + (size_t)(b0 + bi) * 7680);
#pragma unroll 5
    for (int k = 0; k < 15; ++k) {
      int e0 = k * 512 + 2 * t;
      int ch0 = e0 / 15, p0 = e0 - ch0 * 15;
      int e1 = e0 + 1;
      int ch1 = e1 / 15, p1 = e1 - ch1 * 15;
      float f0 = bf2f(Yt[(bi * 16 + p0) * 520 + ch0]);
      float f1 = bf2f(Yt[(bi * 16 + p1) * 520 + ch1]);
      slab[k * 256 + t] = make_float2(
          fmaxf(fmaf(f0, aArr[ch0], bArr[ch0]), 0.f),
          fmaxf(fmaf(f1, aArr[ch1], bArr[ch1]), 0.f));
    }
  }
}

extern "C" void kernel_launch(void* const* d_in, const int* in_sizes, int n_in,
                              void* d_out, int out_size, void* d_ws, size_t ws_size,
                              hipStream_t stream) {
  const float* x = (const float*)d_in[0];
  const float* cw = (const float*)d_in[1];
  // d_in[2] = conv_b: cancelled exactly by training-mode BN -> unused
  const float* gamma = (const float*)d_in[3];
  const float* beta = (const float*)d_in[4];

  unsigned short* wf = (unsigned short*)d_ws;             // 8192*8 bf16 = 128 KB
  float2* Part = (float2*)(wf + 65536);                   // 1024*512 float2 = 4 MB
  float2* AB = Part + (size_t)1024 * 512;                 // 512 float2 = 4 KB

  hipLaunchKernelGGL(k_wprep, dim3(32), dim3(256), 0, stream, cw, wf);
  hipLaunchKernelGGL(k_pass1, dim3(1024), dim3(256), 0, stream, x, wf, Part);
  hipLaunchKernelGGL(k_stats, dim3(64), dim3(256), 0, stream, Part, gamma, beta, AB);
  hipLaunchKernelGGL(k_pass2, dim3(1024), dim3(256), 0, stream, x, wf, AB, (float*)d_out);
}